// Round 7
// baseline (1786.292 us; speedup 1.0000x reference)
//
#include <hip/hip_runtime.h>

#define NUSERS 50000
#define NITEMS 20000
#define NEDGES 400000

typedef _Float16 f16;
typedef __attribute__((ext_vector_type(8))) _Float16 f16x8;
typedef __attribute__((ext_vector_type(4))) _Float16 f16x4;
typedef __attribute__((ext_vector_type(2))) _Float16 f16x2;
typedef __attribute__((ext_vector_type(4))) float f32x4;
typedef __attribute__((ext_vector_type(2))) float f32x2;

// ---------- prep: LDS-tiled weight transpose->f16 (coalesced both sides)
// + folded el/er projections; both relations in one launch ----------
__global__ __launch_bounds__(256) void prep2_k(
    const float* __restrict__ Wa, const float* __restrict__ Aa,
    f16* __restrict__ Bta, float* __restrict__ efa,
    const float* __restrict__ Wb, const float* __restrict__ Ab,
    f16* __restrict__ Btb, float* __restrict__ efb,
    int K, int Nw, int dh) {
  __shared__ float lds[32][33];
  int ntile = (K >> 5) * (Nw >> 5);
  int b = blockIdx.x, t = threadIdx.x;
  if (b < 2 * ntile) {
    const float* W = (b < ntile) ? Wa : Wb;
    f16* Bt = (b < ntile) ? Bta : Btb;
    int tt = (b < ntile) ? b : b - ntile;
    int ntc = Nw >> 5;
    int tr = tt / ntc, tc = tt - tr * ntc;
    int tx = t & 31, ty = t >> 5;
#pragma unroll
    for (int p = 0; p < 4; ++p) {
      int k = tr * 32 + ty + p * 8;
      int n = tc * 32 + tx;
      lds[ty + p * 8][tx] = W[(long)k * Nw + n];
    }
    __syncthreads();
#pragma unroll
    for (int p = 0; p < 4; ++p) {
      int n = tc * 32 + ty + p * 8;
      int k = tr * 32 + tx;
      Bt[(long)n * K + k] = (f16)lds[tx][ty + p * 8];
    }
  } else {
    int idx = (b - 2 * ntile) * 256 + t;
    if (idx >= 2 * K * 8) return;
    const float* W = (idx < K * 8) ? Wa : Wb;
    const float* A = (idx < K * 8) ? Aa : Ab;
    float* ef = (idx < K * 8) ? efa : efb;
    int t2 = (idx < K * 8) ? idx : idx - K * 8;
    int j = t2 / (K * 4);
    int r = t2 - j * K * 4;
    int h = r / K, f = r - h * K;
    const float* Aj = A + j * Nw;   // A[j], shape [4,dh], Nw = 4*dh
    float s = 0.f;
    for (int d = 0; d < dh; ++d) s += W[f * Nw + h * dh + d] * Aj[h * dh + d];
    ef[j * 4 * K + h * K + f] = s;
  }
}

// ---------- f16 MFMA GEMM, user+item fused: C = A[M,K] @ Bt[N,K]^T ----------
__global__ __launch_bounds__(256) void hgemm2_k(const f16* __restrict__ Aa, const f16* __restrict__ Bta,
                                                f16* __restrict__ Ca, int Ma, int gya,
                                                const f16* __restrict__ Ab, const f16* __restrict__ Btb,
                                                f16* __restrict__ Cb, int Mb,
                                                int N, int K) {
  __shared__ f16 As[128 * 32];
  __shared__ f16 Bs[128 * 32];
  int by = blockIdx.y;
  const f16* A; const f16* Bt; f16* C; int M; int row0;
  if (by < gya) { A = Aa; Bt = Bta; C = Ca; M = Ma; row0 = by * 128; }
  else          { A = Ab; Bt = Btb; C = Cb; M = Mb; row0 = (by - gya) * 128; }
  int tid = threadIdx.x;
  int col0 = blockIdx.x * 128;
  int lane = tid & 63, wv = tid >> 6;
  int wr = (wv & 1) * 64, wc = (wv >> 1) * 64;
  int l16 = lane & 15, q = lane >> 4;
  f32x4 acc[4][4] = {};
  int r = tid >> 2, c8 = (tid & 3) * 8;
  for (int k0 = 0; k0 < K; k0 += 32) {
    int ra = min(row0 + r, M - 1);
    uint4 va = *(const uint4*)&A[(long)ra * K + k0 + c8];
    int ra2 = min(row0 + r + 64, M - 1);
    uint4 va2 = *(const uint4*)&A[(long)ra2 * K + k0 + c8];
    uint4 vb = *(const uint4*)&Bt[(long)(col0 + r) * K + k0 + c8];
    uint4 vb2 = *(const uint4*)&Bt[(long)(col0 + r + 64) * K + k0 + c8];
    *(uint4*)&As[r * 32 + c8] = va;
    *(uint4*)&As[(r + 64) * 32 + c8] = va2;
    *(uint4*)&Bs[r * 32 + c8] = vb;
    *(uint4*)&Bs[(r + 64) * 32 + c8] = vb2;
    __syncthreads();
    f16x8 af[4], bfr[4];
#pragma unroll
    for (int i = 0; i < 4; ++i) {
      af[i] = *(const f16x8*)&As[(wr + i * 16 + l16) * 32 + q * 8];
      bfr[i] = *(const f16x8*)&Bs[(wc + i * 16 + l16) * 32 + q * 8];
    }
#pragma unroll
    for (int i = 0; i < 4; ++i)
#pragma unroll
      for (int j = 0; j < 4; ++j)
        acc[i][j] = __builtin_amdgcn_mfma_f32_16x16x32_f16(af[i], bfr[j], acc[i][j], 0, 0, 0);
    __syncthreads();
  }
#pragma unroll
  for (int i = 0; i < 4; ++i) {
#pragma unroll
    for (int reg = 0; reg < 4; ++reg) {
      int rr = row0 + wr + i * 16 + q * 4 + reg;
      if (rr < M) {
#pragma unroll
        for (int j = 0; j < 4; ++j)
          C[(long)rr * N + col0 + wc + j * 16 + l16] = (f16)acc[i][j][reg];
      }
    }
  }
}

// ---------- layer-0: fused f32->f16 convert + el/er folds; WAVE per node ----------
__global__ __launch_bounds__(256) void eler2_k(
    const float* __restrict__ xu, f16* __restrict__ hbu,
    const float* __restrict__ ef_ui, const float* __restrict__ ef_iu,
    float* __restrict__ el_u, float* __restrict__ er_u,
    const float* __restrict__ xi, f16* __restrict__ hbi,
    float* __restrict__ el_i, float* __restrict__ er_i) {
  const int K = 128;
  int wv = threadIdx.x >> 6, lane = threadIdx.x & 63;
  int g = blockIdx.x * 4 + wv;
  const float* x; f16* hb; const float* elf; const float* erf; float* el; float* er; int n;
  if (g < NUSERS)                { x = xu; hb = hbu; elf = ef_ui; erf = ef_iu + 4 * K; el = el_u; er = er_u; n = g; }
  else if (g < NUSERS + NITEMS)  { x = xi; hb = hbi; elf = ef_iu; erf = ef_ui + 4 * K; el = el_i; er = er_i; n = g - NUSERS; }
  else return;
  long base = (long)n * K;
  int c0 = lane * 2;
  f32x2 xv = *(const f32x2*)&x[base + c0];
  f16x2 hv = { (f16)xv[0], (f16)xv[1] };
  *(f16x2*)&hb[base + c0] = hv;
  float p[8];
#pragma unroll
  for (int jj = 0; jj < 8; ++jj) {
    const float* fr = (jj < 4) ? (elf + jj * K) : (erf + (jj - 4) * K);
    f32x2 f2 = *(const f32x2*)&fr[c0];
    p[jj] = xv[0] * f2[0] + xv[1] * f2[1];
  }
#pragma unroll
  for (int off = 32; off; off >>= 1)
#pragma unroll
    for (int jj = 0; jj < 8; ++jj) p[jj] += __shfl_xor(p[jj], off, 64);
  if (lane == 0) {
    *(float4*)&el[n * 4] = make_float4(p[0], p[1], p[2], p[3]);
    *(float4*)&er[n * 4] = make_float4(p[4], p[5], p[6], p[7]);
  }
}

// ---------- CSR build (unified: items [0,NITEMS) then users [NITEMS,NITEMS+NUSERS)) ----------
__global__ void hist_k(const int* __restrict__ ei, int* __restrict__ degi,
                       const int* __restrict__ eu, int* __restrict__ degu) {
  int e = blockIdx.x * blockDim.x + threadIdx.x;
  if (e < NEDGES) atomicAdd(&degi[ei[e]], 1);
  else if (e < 2 * NEDGES) atomicAdd(&degu[eu[e - NEDGES]], 1);
}

__global__ __launch_bounds__(256) void scan1_k(const int* __restrict__ deg,
                                               int* __restrict__ bsum, int N) {
  __shared__ int red[256];
  int base = blockIdx.x * 1024, t = threadIdx.x;
  int s = 0;
#pragma unroll
  for (int j = 0; j < 4; ++j) { int i = base + t * 4 + j; s += (i < N) ? deg[i] : 0; }
  red[t] = s; __syncthreads();
  for (int off = 128; off; off >>= 1) { if (t < off) red[t] += red[t + off]; __syncthreads(); }
  if (t == 0) bsum[blockIdx.x] = red[0];
}

// exclusive block-sum scan + writes rowptr[N] terminator
__global__ void scan2_k(int* __restrict__ bsum, int nb, int* __restrict__ endp, int endv) {
  if (threadIdx.x == 0) {
    int run = 0;
    for (int i = 0; i < nb; ++i) { int v = bsum[i]; bsum[i] = run; run += v; }
    *endp = endv;
  }
}

// scan3 also writes cur[] (folds old copy2_k)
__global__ __launch_bounds__(256) void scan3_k(const int* __restrict__ deg,
                                               const int* __restrict__ bsum,
                                               int* __restrict__ rowptr,
                                               int* __restrict__ cur, int N) {
  __shared__ int tsum[256];
  int base = blockIdx.x * 1024, t = threadIdx.x;
  int v[4]; int s = 0;
#pragma unroll
  for (int j = 0; j < 4; ++j) { int i = base + t * 4 + j; v[j] = (i < N) ? deg[i] : 0; s += v[j]; }
  tsum[t] = s; __syncthreads();
  for (int off = 1; off < 256; off <<= 1) {
    int x = (t >= off) ? tsum[t - off] : 0;
    __syncthreads();
    tsum[t] += x;
    __syncthreads();
  }
  int run = bsum[blockIdx.x] + ((t > 0) ? tsum[t - 1] : 0);
#pragma unroll
  for (int j = 0; j < 4; ++j) {
    int i = base + t * 4 + j;
    if (i < N) { rowptr[i] = run; cur[i] = run; }
    run += v[j];
  }
}

// scatter: plain stores. (NT variant measured WORSE: WRITE 44.5->59.4MB,
// dur 62->67us -- NT kills the partial write-combining L2 provides.)
__global__ void scat_k(const int* __restrict__ ei, const int* __restrict__ eu,
                       int* __restrict__ cur, int* __restrict__ csrsrc) {
  int e = blockIdx.x * blockDim.x + threadIdx.x;
  if (e < NEDGES) {
    int p = atomicAdd(&cur[ei[e]], 1);
    csrsrc[p] = eu[e];
  } else if (e < 2 * NEDGES) {
    int e2 = e - NEDGES;
    int p = atomicAdd(&cur[NITEMS + eu[e2]], 1);
    csrsrc[p] = ei[e2];
  }
}

// ---------- fused segment-softmax + gather (+ optional BN-stats tail); wave per dst ----------
// Output stores NON-TEMPORAL (measured: FETCH -4MB, keeps hs rows in L2).
// STATS=true (L0-L2): block-level LDS accumulation of per-channel sum/sumsq of
// the outputs, flushed with <=4 global atomics/thread -- replaces the separate
// bn_stats pass that re-read the full 36MB aggh buffer. Two sides per block
// possible (item/user boundary) -> st[2][512]. deg==0 waves contribute zeros
// and must reach the barriers (no early return in STATS path).
template <int W, int DH, typename OUT, bool STATS>
__global__ __launch_bounds__(256) void agg_k(
    const float* __restrict__ elA, const float* __restrict__ erA,
    const int* __restrict__ rpA, const int* __restrict__ srcA,
    const f16* __restrict__ hsA, OUT* __restrict__ outA, int nA, float* __restrict__ SA,
    const float* __restrict__ elB, const float* __restrict__ erB,
    const int* __restrict__ rpB, const int* __restrict__ srcB,
    const f16* __restrict__ hsB, OUT* __restrict__ outB, int nB, float* __restrict__ SB) {
  constexpr int CPL = W >> 6;                   // channels per lane
  constexpr int SHIFT = (W == 256) ? 9 : 8;     // log2(W * sizeof(f16))
  constexpr bool OF16 = (sizeof(OUT) == 2);
  __shared__ float alds[4][256];   // [wave][slot*4 + head]
  __shared__ int soff[4][64];      // [wave][slot] = src row byte offset
  __shared__ float st[STATS ? 2 : 1][STATS ? 512 : 1];  // [side][ch | 256+ch]
  int wv = threadIdx.x >> 6;
  int g = blockIdx.x * 4 + wv;
  int lane = threadIdx.x & 63;
  if constexpr (STATS) {
    int t = threadIdx.x;
    st[0][t] = 0.f; st[0][t + 256] = 0.f;
    st[1][t] = 0.f; st[1][t + 256] = 0.f;
    __syncthreads();
  }
  const float* el; const float* er; const int* rp; const int* srcv;
  const f16* hs; OUT* outp; int d; int side = 0; bool live = true;
  if (g < nA)           { el = elA; er = erA; rp = rpA; srcv = srcA; hs = hsA; outp = outA; d = g; side = 0; }
  else if (g < nA + nB) { el = elB; er = erB; rp = rpB; srcv = srcB; hs = hsB; outp = outB; d = g - nA; side = 1; }
  else {
    if constexpr (!STATS) return;
    live = false; d = 0;
  }
  const float NEG = -3.0e38f;
  float vals[CPL];
#pragma unroll
  for (int q = 0; q < CPL; ++q) vals[q] = 0.f;
  int c0 = lane * CPL;
  int h = c0 / DH;
  int deg = 0;
  long obase = 0;
  if (live) {
    int s0 = rp[d], s1 = rp[d + 1];
    deg = s1 - s0;
    obase = (long)d * W + c0;
    if (deg == 0) {
#pragma unroll
      for (int q = 0; q < CPL; ++q) outp[obase + q] = (OUT)0.f;
    } else {
      float acc[CPL];
#pragma unroll
      for (int q = 0; q < CPL; ++q) acc[q] = 0.f;
      float inv;
      if (deg <= 64) {
        int hh = lane & 3, p = lane >> 2;
        float er_h = er[d * 4 + hh];
        float vv[4];
        float vmax = NEG;
#pragma unroll
        for (int j = 0; j < 4; ++j) {
          int slot = j * 16 + p;
          vv[j] = NEG;
          if (slot < deg) {
            int sj = srcv[s0 + slot];
            if (hh == 0) soff[wv][slot] = sj << SHIFT;
            float v = el[sj * 4 + hh] + er_h;
            v = v > 0.f ? v : 0.2f * v;
            vv[j] = v;
            vmax = fmaxf(vmax, v);
          }
        }
#pragma unroll
        for (int off = 4; off < 64; off <<= 1) vmax = fmaxf(vmax, __shfl_xor(vmax, off, 64));
        float ssum = 0.f;
#pragma unroll
        for (int j = 0; j < 4; ++j) {
          int slot = j * 16 + p;
          if (slot < deg) {
            float e = expf(vv[j] - vmax);
            alds[wv][slot * 4 + hh] = e;
            ssum += e;
          } else {
            alds[wv][slot * 4 + hh] = 0.f;       // zero-pad alpha
            if (hh == 0) soff[wv][slot] = 0;     // pad offset -> row 0 (always cached)
          }
        }
#pragma unroll
        for (int off = 4; off < 64; off <<= 1) ssum += __shfl_xor(ssum, off, 64);
        float Sh = __shfl(ssum, (lane & ~3) | h, 64);
        inv = 1.0f / Sh;
        const char* hbase = (const char*)hs + (size_t)c0 * sizeof(f16);
        int degp = (deg + 3) & ~3;
        for (int j = 0; j < degp; j += 4) {
          float aj[4]; int oj[4];
#pragma unroll
          for (int u = 0; u < 4; ++u) {
            aj[u] = alds[wv][(j + u) * 4 + h];
            oj[u] = soff[wv][j + u];
          }
          if constexpr (CPL == 4) {
            f16x4 vj[4];
#pragma unroll
            for (int u = 0; u < 4; ++u)
              vj[u] = *(const f16x4*)(hbase + (size_t)(unsigned)oj[u]);
#pragma unroll
            for (int u = 0; u < 4; ++u) {
              acc[0] += aj[u] * (float)vj[u][0];
              acc[1] += aj[u] * (float)vj[u][1];
              acc[2] += aj[u] * (float)vj[u][2];
              acc[3] += aj[u] * (float)vj[u][3];
            }
          } else {
            f16x2 vj[4];
#pragma unroll
            for (int u = 0; u < 4; ++u)
              vj[u] = *(const f16x2*)(hbase + (size_t)(unsigned)oj[u]);
#pragma unroll
            for (int u = 0; u < 4; ++u) {
              acc[0] += aj[u] * (float)vj[u][0];
              acc[1] += aj[u] * (float)vj[u][1];
            }
          }
        }
      } else {
        // ---- generic fallback (deg > 64): strided two-pass + serial gather ----
        float4 er4 = *(const float4*)&er[d * 4];
        float m0 = NEG, m1 = NEG, m2 = NEG, m3 = NEG;
        for (int k = s0 + lane; k < s1; k += 64) {
          int s = srcv[k];
          float4 e4 = *(const float4*)&el[s * 4];
          float v;
          v = e4.x + er4.x; v = v > 0.f ? v : 0.2f * v; m0 = fmaxf(m0, v);
          v = e4.y + er4.y; v = v > 0.f ? v : 0.2f * v; m1 = fmaxf(m1, v);
          v = e4.z + er4.z; v = v > 0.f ? v : 0.2f * v; m2 = fmaxf(m2, v);
          v = e4.w + er4.w; v = v > 0.f ? v : 0.2f * v; m3 = fmaxf(m3, v);
        }
#pragma unroll
        for (int off = 32; off; off >>= 1) {
          m0 = fmaxf(m0, __shfl_xor(m0, off, 64));
          m1 = fmaxf(m1, __shfl_xor(m1, off, 64));
          m2 = fmaxf(m2, __shfl_xor(m2, off, 64));
          m3 = fmaxf(m3, __shfl_xor(m3, off, 64));
        }
        float S0 = 0.f, S1 = 0.f, S2 = 0.f, S3 = 0.f;
        for (int k = s0 + lane; k < s1; k += 64) {
          int s = srcv[k];
          float4 e4 = *(const float4*)&el[s * 4];
          float v;
          v = e4.x + er4.x; v = v > 0.f ? v : 0.2f * v; S0 += expf(v - m0);
          v = e4.y + er4.y; v = v > 0.f ? v : 0.2f * v; S1 += expf(v - m1);
          v = e4.z + er4.z; v = v > 0.f ? v : 0.2f * v; S2 += expf(v - m2);
          v = e4.w + er4.w; v = v > 0.f ? v : 0.2f * v; S3 += expf(v - m3);
        }
#pragma unroll
        for (int off = 32; off; off >>= 1) {
          S0 += __shfl_xor(S0, off, 64);
          S1 += __shfl_xor(S1, off, 64);
          S2 += __shfl_xor(S2, off, 64);
          S3 += __shfl_xor(S3, off, 64);
        }
        float mh = h == 0 ? m0 : h == 1 ? m1 : h == 2 ? m2 : m3;
        float Sh = h == 0 ? S0 : h == 1 ? S1 : h == 2 ? S2 : S3;
        float erh = h == 0 ? er4.x : h == 1 ? er4.y : h == 2 ? er4.z : er4.w;
        inv = 1.0f / Sh;
        for (int k = s0; k < s1; ++k) {
          int s = srcv[k];
          float v = el[s * 4 + h] + erh; v = v > 0.f ? v : 0.2f * v;
          float a = expf(v - mh);
          const f16* row = &hs[(long)s * W + c0];
          if constexpr (CPL == 4) {
            f16x4 hv = *(const f16x4*)row;
            acc[0] += a * (float)hv[0]; acc[1] += a * (float)hv[1];
            acc[2] += a * (float)hv[2]; acc[3] += a * (float)hv[3];
          } else {
            f16x2 hv = *(const f16x2*)row;
            acc[0] += a * (float)hv[0]; acc[1] += a * (float)hv[1];
          }
        }
      }
#pragma unroll
      for (int q = 0; q < CPL; ++q) vals[q] = acc[q] * inv;
      if constexpr (OF16) {
        if constexpr (CPL == 4) {
          f16x4 o = { (f16)vals[0], (f16)vals[1], (f16)vals[2], (f16)vals[3] };
          __builtin_nontemporal_store(o, (f16x4*)&outp[obase]);
        } else {
          f16x2 o = { (f16)vals[0], (f16)vals[1] };
          __builtin_nontemporal_store(o, (f16x2*)&outp[obase]);
        }
      } else {
        if constexpr (CPL == 4) {
          f32x4 o = { vals[0], vals[1], vals[2], vals[3] };
          __builtin_nontemporal_store(o, (f32x4*)&outp[obase]);
        } else {
          f32x2 o = { vals[0], vals[1] };
          __builtin_nontemporal_store(o, (f32x2*)&outp[obase]);
        }
      }
    }
  }
  if constexpr (STATS) {
    if (live) {
#pragma unroll
      for (int q = 0; q < CPL; ++q) {
        atomicAdd(&st[side][c0 + q], vals[q]);
        atomicAdd(&st[side][256 + c0 + q], vals[q] * vals[q]);
      }
    }
    __syncthreads();
    int t = threadIdx.x;
    float a0 = st[0][t], a0q = st[0][256 + t];
    float a1 = st[1][t], a1q = st[1][256 + t];
    if (a0 != 0.f || a0q != 0.f) { atomicAdd(&SA[t], a0); atomicAdd(&SA[256 + t], a0q); }
    if (a1 != 0.f || a1q != 0.f) { atomicAdd(&SB[t], a1); atomicAdd(&SB[256 + t], a1q); }
  }
}

// ---------- fused BN apply + activation -> f16 AND next-layer el/er; WAVE per node ----------
__global__ __launch_bounds__(256) void bn_fused_k(
    const f16* __restrict__ xu, const float* __restrict__ su, const float* __restrict__ gbu,
    f16* __restrict__ yu, int Nu,
    const f16* __restrict__ xi, const float* __restrict__ si, const float* __restrict__ gbi,
    f16* __restrict__ yi, int Ni,
    const float* __restrict__ efu, const float* __restrict__ efiu,   // next-layer folds, K=256
    float* __restrict__ el_u, float* __restrict__ er_u,
    float* __restrict__ el_i, float* __restrict__ er_i, int act) {
  const int Kn = 256;
  int wv = threadIdx.x >> 6, lane = threadIdx.x & 63;
  int g = blockIdx.x * 4 + wv;
  const f16* x; const float* sums; const float* gb; f16* y; int n; int N;
  const float* elf; const float* erf; float* el; float* er;
  if (g < Nu)           { x = xu; sums = su; gb = gbu; y = yu; n = g; N = Nu; elf = efu;  erf = efiu + 4 * Kn; el = el_u; er = er_u; }
  else if (g < Nu + Ni) { x = xi; sums = si; gb = gbi; y = yi; n = g - Nu; N = Ni; elf = efiu; erf = efu + 4 * Kn;  el = el_i; er = er_i; }
  else return;
  long base = (long)n * 256;
  int c0 = lane * 4;
  f16x4 xv = *(const f16x4*)&x[base + c0];
  float4 sm = *(const float4*)&sums[c0];
  float4 q2 = *(const float4*)&sums[256 + c0];
  float4 gg = *(const float4*)&gb[c0];
  float4 bb = *(const float4*)&gb[256 + c0];
  float ms[4] = { sm.x, sm.y, sm.z, sm.w };
  float qs[4] = { q2.x, q2.y, q2.z, q2.w };
  float gs[4] = { gg.x, gg.y, gg.z, gg.w };
  float bs[4] = { bb.x, bb.y, bb.z, bb.w };
  float inv_n = 1.0f / (float)N;
  float v[4];
  f16x4 ov;
#pragma unroll
  for (int q = 0; q < 4; ++q) {
    float mean = ms[q] * inv_n;
    float var = qs[q] * inv_n - mean * mean;
    float t = gs[q] * ((float)xv[q] - mean) * rsqrtf(var + 1e-5f) + bs[q];
    t = act ? tanhf(t) : (t > 0.f ? t : 0.01f * t);
    v[q] = t;
    ov[q] = (f16)t;
  }
  *(f16x4*)&y[base + c0] = ov;
  float p[8];
#pragma unroll
  for (int jj = 0; jj < 8; ++jj) {
    const float* fr = (jj < 4) ? (elf + jj * Kn) : (erf + (jj - 4) * Kn);
    float4 f4 = *(const float4*)&fr[c0];
    p[jj] = v[0] * f4.x + v[1] * f4.y + v[2] * f4.z + v[3] * f4.w;
  }
#pragma unroll
  for (int off = 32; off; off >>= 1)
#pragma unroll
    for (int jj = 0; jj < 8; ++jj) p[jj] += __shfl_xor(p[jj], off, 64);
  if (lane == 0) {
    *(float4*)&el[n * 4] = make_float4(p[0], p[1], p[2], p[3]);
    *(float4*)&er[n * 4] = make_float4(p[4], p[5], p[6], p[7]);
  }
}

extern "C" void kernel_launch(void* const* d_in, const int* in_sizes, int n_in,
                              void* d_out, int out_size, void* d_ws, size_t ws_size,
                              hipStream_t stream) {
  const float* x_user = (const float*)d_in[0];
  const float* x_item = (const float*)d_in[1];
  const int* eu = (const int*)d_in[2];
  const int* ei = (const int*)d_in[3];
  const float *Wm[4][2], *Am[4][2];
  for (int L = 0; L < 4; ++L) {
    Wm[L][0] = (const float*)d_in[4 + L * 4 + 0];
    Am[L][0] = (const float*)d_in[4 + L * 4 + 1];
    Wm[L][1] = (const float*)d_in[4 + L * 4 + 2];
    Am[L][1] = (const float*)d_in[4 + L * 4 + 3];
  }
  const float* bnu = (const float*)d_in[20];
  const float* bni = (const float*)d_in[21];
  float* out = (float*)d_out;

  const int NALL = NITEMS + NUSERS;

  float* ws = (float*)d_ws;
  size_t o = 0;
  float* el_u = ws + o; o += (size_t)NUSERS * 4;
  float* er_u = ws + o; o += (size_t)NUSERS * 4;
  float* el_i = ws + o; o += (size_t)NITEMS * 4;
  float* er_i = ws + o; o += (size_t)NITEMS * 4;
  float* ef_all[4][2];
  for (int L = 0; L < 4; ++L)
    for (int rl = 0; rl < 2; ++rl) { ef_all[L][rl] = ws + o; o += 2048; }
  // f16 buffers (offsets in float units; all 16B aligned)
  f16* hb_u   = (f16*)(ws + o); o += (size_t)NUSERS * 128;
  f16* hb_i   = (f16*)(ws + o); o += (size_t)NITEMS * 128;
  f16* hsb_u  = (f16*)(ws + o); o += (size_t)NUSERS * 128;
  f16* hsb_i  = (f16*)(ws + o); o += (size_t)NITEMS * 128;
  f16* aggh_u = (f16*)(ws + o); o += (size_t)NUSERS * 128;
  f16* aggh_i = (f16*)(ws + o); o += (size_t)NITEMS * 128;
  f16* Bt_all[4][2];
  for (int L = 0; L < 4; ++L) {
    int K = (L == 0) ? 128 : 256;
    int W = (L == 3) ? 128 : 256;
    for (int rl = 0; rl < 2; ++rl) { Bt_all[L][rl] = (f16*)(ws + o); o += (size_t)K * W / 2; }
  }
  // BN sums (3 layers x (512u + 512i)) + unified CSR deg: contiguous => single memset
  float* bns_all = ws + o; o += 3 * 1024;
  int* deg_all    = (int*)(ws + o); o += NALL;          // items then users
  int* rowptr_all = (int*)(ws + o); o += NALL + 4;      // unified rowptr; users offset by NEDGES
  int* cur_all    = (int*)(ws + o); o += NALL;
  int* bsum       = (int*)(ws + o); o += 256;
  int* csrsrc_all = (int*)(ws + o); o += 2 * NEDGES + 4;

  const int gE2 = (2 * NEDGES + 255) / 256;
  const int nb = (NALL + 1023) / 1024;
  const int gNode = (NALL + 3) / 4;

  // ---- zero BN sums + deg in one memset; unified CSR build (once) ----
  hipMemsetAsync(bns_all, 0, (3 * 1024 + NALL) * sizeof(float), stream);
  hist_k<<<dim3(gE2), dim3(256), 0, stream>>>(ei, deg_all, eu, deg_all + NITEMS);
  scan1_k<<<dim3(nb), dim3(256), 0, stream>>>(deg_all, bsum, NALL);
  scan2_k<<<dim3(1), dim3(64), 0, stream>>>(bsum, nb, rowptr_all + NALL, 2 * NEDGES);
  scan3_k<<<dim3(nb), dim3(256), 0, stream>>>(deg_all, bsum, rowptr_all, cur_all, NALL);
  scat_k<<<dim3(gE2), dim3(256), 0, stream>>>(ei, eu, cur_all, csrsrc_all);

  // CSR views: items at rowptr_all[0..NITEMS], users at rowptr_all[NITEMS..NALL]
  const int* rowptr_i = rowptr_all;
  const int* rowptr_u = rowptr_all + NITEMS;

  // ---- all layer preps upfront (tiled Bt transpose + el/er folds) ----
  for (int L = 0; L < 4; ++L) {
    int K = (L == 0) ? 128 : 256;
    int dh = (L == 3) ? 32 : 64;
    int W = 4 * dh;
    int ntile2 = 2 * (K / 32) * (W / 32);
    int gef = (2 * K * 8 + 255) / 256;
    prep2_k<<<dim3(ntile2 + gef), dim3(256), 0, stream>>>(
        Wm[L][0], Am[L][0], Bt_all[L][0], ef_all[L][0],
        Wm[L][1], Am[L][1], Bt_all[L][1], ef_all[L][1], K, W, dh);
  }

  // layer-0: fused f32->f16 convert + el/er (wave per node)
  eler2_k<<<dim3(gNode), dim3(256), 0, stream>>>(
      x_user, hb_u, ef_all[0][0], ef_all[0][1], el_u, er_u,
      x_item, hb_i, el_i, er_i);

  int K = 128;
  const int gAgg = gNode;
  const int gya = (NUSERS + 127) / 128, gyb = (NITEMS + 127) / 128;
  for (int L = 0; L < 4; ++L) {
    const int dh = (L == 3) ? 32 : 64;
    const int W = 4 * dh;

    hgemm2_k<<<dim3(W / 128, gya + gyb), dim3(256), 0, stream>>>(
        hb_u, Bt_all[L][0], hsb_u, NUSERS, gya, hb_i, Bt_all[L][1], hsb_i, NITEMS, W, K);

    if (L < 3) {
      float* su = bns_all + (size_t)L * 1024;
      float* si = su + 512;
      agg_k<256, 64, f16, true><<<dim3(gAgg), dim3(256), 0, stream>>>(
          el_u, er_i, rowptr_i, csrsrc_all, hsb_u, aggh_i, NITEMS, si,
          el_i, er_u, rowptr_u, csrsrc_all, hsb_i, aggh_u, NUSERS, su);
      bn_fused_k<<<dim3(gNode), dim3(256), 0, stream>>>(
          aggh_u, su, bnu + L * 512, hb_u, NUSERS,
          aggh_i, si, bni + L * 512, hb_i, NITEMS,
          ef_all[L + 1][0], ef_all[L + 1][1],
          el_u, er_u, el_i, er_i, L == 2);
      K = 256;
    } else {
      agg_k<128, 32, float, false><<<dim3(gAgg), dim3(256), 0, stream>>>(
          el_u, er_i, rowptr_i, csrsrc_all, hsb_u, out + (size_t)NUSERS * 128, NITEMS, nullptr,
          el_i, er_u, rowptr_u, csrsrc_all, hsb_i, out, NUSERS, nullptr);
    }
  }
}

// Round 8
// 862.520 us; speedup vs baseline: 2.0710x; 2.0710x over previous
//
#include <hip/hip_runtime.h>

#define NUSERS 50000
#define NITEMS 20000
#define NEDGES 400000

typedef _Float16 f16;
typedef __attribute__((ext_vector_type(8))) _Float16 f16x8;
typedef __attribute__((ext_vector_type(4))) _Float16 f16x4;
typedef __attribute__((ext_vector_type(2))) _Float16 f16x2;
typedef __attribute__((ext_vector_type(4))) float f32x4;
typedef __attribute__((ext_vector_type(2))) float f32x2;

// ---------- prep: LDS-tiled weight transpose->f16 (coalesced both sides)
// + folded el/er projections; both relations in one launch ----------
__global__ __launch_bounds__(256) void prep2_k(
    const float* __restrict__ Wa, const float* __restrict__ Aa,
    f16* __restrict__ Bta, float* __restrict__ efa,
    const float* __restrict__ Wb, const float* __restrict__ Ab,
    f16* __restrict__ Btb, float* __restrict__ efb,
    int K, int Nw, int dh) {
  __shared__ float lds[32][33];
  int ntile = (K >> 5) * (Nw >> 5);
  int b = blockIdx.x, t = threadIdx.x;
  if (b < 2 * ntile) {
    const float* W = (b < ntile) ? Wa : Wb;
    f16* Bt = (b < ntile) ? Bta : Btb;
    int tt = (b < ntile) ? b : b - ntile;
    int ntc = Nw >> 5;
    int tr = tt / ntc, tc = tt - tr * ntc;
    int tx = t & 31, ty = t >> 5;
#pragma unroll
    for (int p = 0; p < 4; ++p) {
      int k = tr * 32 + ty + p * 8;
      int n = tc * 32 + tx;
      lds[ty + p * 8][tx] = W[(long)k * Nw + n];
    }
    __syncthreads();
#pragma unroll
    for (int p = 0; p < 4; ++p) {
      int n = tc * 32 + ty + p * 8;
      int k = tr * 32 + tx;
      Bt[(long)n * K + k] = (f16)lds[tx][ty + p * 8];
    }
  } else {
    int idx = (b - 2 * ntile) * 256 + t;
    if (idx >= 2 * K * 8) return;
    const float* W = (idx < K * 8) ? Wa : Wb;
    const float* A = (idx < K * 8) ? Aa : Ab;
    float* ef = (idx < K * 8) ? efa : efb;
    int t2 = (idx < K * 8) ? idx : idx - K * 8;
    int j = t2 / (K * 4);
    int r = t2 - j * K * 4;
    int h = r / K, f = r - h * K;
    const float* Aj = A + j * Nw;   // A[j], shape [4,dh], Nw = 4*dh
    float s = 0.f;
    for (int d = 0; d < dh; ++d) s += W[f * Nw + h * dh + d] * Aj[h * dh + d];
    ef[j * 4 * K + h * K + f] = s;
  }
}

// ---------- f16 MFMA GEMM, user+item fused: C = A[M,K] @ Bt[N,K]^T ----------
__global__ __launch_bounds__(256) void hgemm2_k(const f16* __restrict__ Aa, const f16* __restrict__ Bta,
                                                f16* __restrict__ Ca, int Ma, int gya,
                                                const f16* __restrict__ Ab, const f16* __restrict__ Btb,
                                                f16* __restrict__ Cb, int Mb,
                                                int N, int K) {
  __shared__ f16 As[128 * 32];
  __shared__ f16 Bs[128 * 32];
  int by = blockIdx.y;
  const f16* A; const f16* Bt; f16* C; int M; int row0;
  if (by < gya) { A = Aa; Bt = Bta; C = Ca; M = Ma; row0 = by * 128; }
  else          { A = Ab; Bt = Btb; C = Cb; M = Mb; row0 = (by - gya) * 128; }
  int tid = threadIdx.x;
  int col0 = blockIdx.x * 128;
  int lane = tid & 63, wv = tid >> 6;
  int wr = (wv & 1) * 64, wc = (wv >> 1) * 64;
  int l16 = lane & 15, q = lane >> 4;
  f32x4 acc[4][4] = {};
  int r = tid >> 2, c8 = (tid & 3) * 8;
  for (int k0 = 0; k0 < K; k0 += 32) {
    int ra = min(row0 + r, M - 1);
    uint4 va = *(const uint4*)&A[(long)ra * K + k0 + c8];
    int ra2 = min(row0 + r + 64, M - 1);
    uint4 va2 = *(const uint4*)&A[(long)ra2 * K + k0 + c8];
    uint4 vb = *(const uint4*)&Bt[(long)(col0 + r) * K + k0 + c8];
    uint4 vb2 = *(const uint4*)&Bt[(long)(col0 + r + 64) * K + k0 + c8];
    *(uint4*)&As[r * 32 + c8] = va;
    *(uint4*)&As[(r + 64) * 32 + c8] = va2;
    *(uint4*)&Bs[r * 32 + c8] = vb;
    *(uint4*)&Bs[(r + 64) * 32 + c8] = vb2;
    __syncthreads();
    f16x8 af[4], bfr[4];
#pragma unroll
    for (int i = 0; i < 4; ++i) {
      af[i] = *(const f16x8*)&As[(wr + i * 16 + l16) * 32 + q * 8];
      bfr[i] = *(const f16x8*)&Bs[(wc + i * 16 + l16) * 32 + q * 8];
    }
#pragma unroll
    for (int i = 0; i < 4; ++i)
#pragma unroll
      for (int j = 0; j < 4; ++j)
        acc[i][j] = __builtin_amdgcn_mfma_f32_16x16x32_f16(af[i], bfr[j], acc[i][j], 0, 0, 0);
    __syncthreads();
  }
#pragma unroll
  for (int i = 0; i < 4; ++i) {
#pragma unroll
    for (int reg = 0; reg < 4; ++reg) {
      int rr = row0 + wr + i * 16 + q * 4 + reg;
      if (rr < M) {
#pragma unroll
        for (int j = 0; j < 4; ++j)
          C[(long)rr * N + col0 + wc + j * 16 + l16] = (f16)acc[i][j][reg];
      }
    }
  }
}

// ---------- layer-0: fused f32->f16 convert + el/er folds; WAVE per node ----------
__global__ __launch_bounds__(256) void eler2_k(
    const float* __restrict__ xu, f16* __restrict__ hbu,
    const float* __restrict__ ef_ui, const float* __restrict__ ef_iu,
    float* __restrict__ el_u, float* __restrict__ er_u,
    const float* __restrict__ xi, f16* __restrict__ hbi,
    float* __restrict__ el_i, float* __restrict__ er_i) {
  const int K = 128;
  int wv = threadIdx.x >> 6, lane = threadIdx.x & 63;
  int g = blockIdx.x * 4 + wv;
  const float* x; f16* hb; const float* elf; const float* erf; float* el; float* er; int n;
  if (g < NUSERS)                { x = xu; hb = hbu; elf = ef_ui; erf = ef_iu + 4 * K; el = el_u; er = er_u; n = g; }
  else if (g < NUSERS + NITEMS)  { x = xi; hb = hbi; elf = ef_iu; erf = ef_ui + 4 * K; el = el_i; er = er_i; n = g - NUSERS; }
  else return;
  long base = (long)n * K;
  int c0 = lane * 2;
  f32x2 xv = *(const f32x2*)&x[base + c0];
  f16x2 hv = { (f16)xv[0], (f16)xv[1] };
  *(f16x2*)&hb[base + c0] = hv;
  float p[8];
#pragma unroll
  for (int jj = 0; jj < 8; ++jj) {
    const float* fr = (jj < 4) ? (elf + jj * K) : (erf + (jj - 4) * K);
    f32x2 f2 = *(const f32x2*)&fr[c0];
    p[jj] = xv[0] * f2[0] + xv[1] * f2[1];
  }
#pragma unroll
  for (int off = 32; off; off >>= 1)
#pragma unroll
    for (int jj = 0; jj < 8; ++jj) p[jj] += __shfl_xor(p[jj], off, 64);
  if (lane == 0) {
    *(float4*)&el[n * 4] = make_float4(p[0], p[1], p[2], p[3]);
    *(float4*)&er[n * 4] = make_float4(p[4], p[5], p[6], p[7]);
  }
}

// ---------- CSR build (unified: items [0,NITEMS) then users [NITEMS,NITEMS+NUSERS)) ----------
__global__ void hist_k(const int* __restrict__ ei, int* __restrict__ degi,
                       const int* __restrict__ eu, int* __restrict__ degu) {
  int e = blockIdx.x * blockDim.x + threadIdx.x;
  if (e < NEDGES) atomicAdd(&degi[ei[e]], 1);
  else if (e < 2 * NEDGES) atomicAdd(&degu[eu[e - NEDGES]], 1);
}

__global__ __launch_bounds__(256) void scan1_k(const int* __restrict__ deg,
                                               int* __restrict__ bsum, int N) {
  __shared__ int red[256];
  int base = blockIdx.x * 1024, t = threadIdx.x;
  int s = 0;
#pragma unroll
  for (int j = 0; j < 4; ++j) { int i = base + t * 4 + j; s += (i < N) ? deg[i] : 0; }
  red[t] = s; __syncthreads();
  for (int off = 128; off; off >>= 1) { if (t < off) red[t] += red[t + off]; __syncthreads(); }
  if (t == 0) bsum[blockIdx.x] = red[0];
}

// exclusive block-sum scan + writes rowptr[N] terminator
__global__ void scan2_k(int* __restrict__ bsum, int nb, int* __restrict__ endp, int endv) {
  if (threadIdx.x == 0) {
    int run = 0;
    for (int i = 0; i < nb; ++i) { int v = bsum[i]; bsum[i] = run; run += v; }
    *endp = endv;
  }
}

// scan3 also writes cur[] (folds old copy2_k)
__global__ __launch_bounds__(256) void scan3_k(const int* __restrict__ deg,
                                               const int* __restrict__ bsum,
                                               int* __restrict__ rowptr,
                                               int* __restrict__ cur, int N) {
  __shared__ int tsum[256];
  int base = blockIdx.x * 1024, t = threadIdx.x;
  int v[4]; int s = 0;
#pragma unroll
  for (int j = 0; j < 4; ++j) { int i = base + t * 4 + j; v[j] = (i < N) ? deg[i] : 0; s += v[j]; }
  tsum[t] = s; __syncthreads();
  for (int off = 1; off < 256; off <<= 1) {
    int x = (t >= off) ? tsum[t - off] : 0;
    __syncthreads();
    tsum[t] += x;
    __syncthreads();
  }
  int run = bsum[blockIdx.x] + ((t > 0) ? tsum[t - 1] : 0);
#pragma unroll
  for (int j = 0; j < 4; ++j) {
    int i = base + t * 4 + j;
    if (i < N) { rowptr[i] = run; cur[i] = run; }
    run += v[j];
  }
}

// scatter via atomicExch: plain 4B scattered stores dirty lines in the issuing
// XCD's private L2; 8 XCDs sharing the 3.2MB region bounce partial dirty lines
// through HBM (measured 44.5MB writes for 3.2MB payload). Device-scope atomics
// execute at the shared memory-side cache -- one home location per line, no
// cross-XCD replication. (NT stores measured WORSE: 59.4MB -- they remove the
// only merge point.)
__global__ void scat_k(const int* __restrict__ ei, const int* __restrict__ eu,
                       int* __restrict__ cur, int* __restrict__ csrsrc) {
  int e = blockIdx.x * blockDim.x + threadIdx.x;
  if (e < NEDGES) {
    int p = atomicAdd(&cur[ei[e]], 1);
    atomicExch(&csrsrc[p], eu[e]);
  } else if (e < 2 * NEDGES) {
    int e2 = e - NEDGES;
    int p = atomicAdd(&cur[NITEMS + eu[e2]], 1);
    atomicExch(&csrsrc[p], ei[e2]);
  }
}

// ---------- fused segment-softmax + gather; wave per dst ----------
// Output stores NON-TEMPORAL (measured: FETCH -4MB, keeps hs rows in L2).
template <int W, int DH, typename OUT>
__global__ __launch_bounds__(256) void agg_k(
    const float* __restrict__ elA, const float* __restrict__ erA,
    const int* __restrict__ rpA, const int* __restrict__ srcA,
    const f16* __restrict__ hsA, OUT* __restrict__ outA, int nA,
    const float* __restrict__ elB, const float* __restrict__ erB,
    const int* __restrict__ rpB, const int* __restrict__ srcB,
    const f16* __restrict__ hsB, OUT* __restrict__ outB, int nB) {
  constexpr int CPL = W >> 6;                   // channels per lane
  constexpr int SHIFT = (W == 256) ? 9 : 8;     // log2(W * sizeof(f16))
  constexpr bool OF16 = (sizeof(OUT) == 2);
  __shared__ float alds[4][256];   // [wave][slot*4 + head]
  __shared__ int soff[4][64];      // [wave][slot] = src row byte offset
  int wv = threadIdx.x >> 6;
  int g = blockIdx.x * 4 + wv;
  int lane = threadIdx.x & 63;
  const float* el; const float* er; const int* rp; const int* srcv;
  const f16* hs; OUT* outp; int d;
  if (g < nA)           { el = elA; er = erA; rp = rpA; srcv = srcA; hs = hsA; outp = outA; d = g; }
  else if (g < nA + nB) { el = elB; er = erB; rp = rpB; srcv = srcB; hs = hsB; outp = outB; d = g - nA; }
  else return;
  int s0 = rp[d], s1 = rp[d + 1];
  int deg = s1 - s0;
  int c0 = lane * CPL;
  int h = c0 / DH;
  long obase = (long)d * W + c0;
  if (deg == 0) {
#pragma unroll
    for (int q = 0; q < CPL; ++q) outp[obase + q] = (OUT)0.f;
    return;
  }
  const float NEG = -3.0e38f;
  float acc[CPL];
#pragma unroll
  for (int q = 0; q < CPL; ++q) acc[q] = 0.f;
  float inv;

  if (deg <= 64) {
    int hh = lane & 3, p = lane >> 2;
    float er_h = er[d * 4 + hh];
    float vv[4];
    float vmax = NEG;
#pragma unroll
    for (int j = 0; j < 4; ++j) {
      int slot = j * 16 + p;
      vv[j] = NEG;
      if (slot < deg) {
        int sj = srcv[s0 + slot];
        if (hh == 0) soff[wv][slot] = sj << SHIFT;
        float v = el[sj * 4 + hh] + er_h;
        v = v > 0.f ? v : 0.2f * v;
        vv[j] = v;
        vmax = fmaxf(vmax, v);
      }
    }
#pragma unroll
    for (int off = 4; off < 64; off <<= 1) vmax = fmaxf(vmax, __shfl_xor(vmax, off, 64));
    float ssum = 0.f;
#pragma unroll
    for (int j = 0; j < 4; ++j) {
      int slot = j * 16 + p;
      if (slot < deg) {
        float e = expf(vv[j] - vmax);
        alds[wv][slot * 4 + hh] = e;
        ssum += e;
      } else {
        alds[wv][slot * 4 + hh] = 0.f;       // zero-pad alpha
        if (hh == 0) soff[wv][slot] = 0;     // pad offset -> row 0 (always cached)
      }
    }
#pragma unroll
    for (int off = 4; off < 64; off <<= 1) ssum += __shfl_xor(ssum, off, 64);
    float Sh = __shfl(ssum, (lane & ~3) | h, 64);
    inv = 1.0f / Sh;
    const char* hbase = (const char*)hs + (size_t)c0 * sizeof(f16);
    int degp = (deg + 3) & ~3;
    for (int j = 0; j < degp; j += 4) {
      float aj[4]; int oj[4];
#pragma unroll
      for (int u = 0; u < 4; ++u) {
        aj[u] = alds[wv][(j + u) * 4 + h];
        oj[u] = soff[wv][j + u];
      }
      if constexpr (CPL == 4) {
        f16x4 vj[4];
#pragma unroll
        for (int u = 0; u < 4; ++u)
          vj[u] = *(const f16x4*)(hbase + (size_t)(unsigned)oj[u]);
#pragma unroll
        for (int u = 0; u < 4; ++u) {
          acc[0] += aj[u] * (float)vj[u][0];
          acc[1] += aj[u] * (float)vj[u][1];
          acc[2] += aj[u] * (float)vj[u][2];
          acc[3] += aj[u] * (float)vj[u][3];
        }
      } else {
        f16x2 vj[4];
#pragma unroll
        for (int u = 0; u < 4; ++u)
          vj[u] = *(const f16x2*)(hbase + (size_t)(unsigned)oj[u]);
#pragma unroll
        for (int u = 0; u < 4; ++u) {
          acc[0] += aj[u] * (float)vj[u][0];
          acc[1] += aj[u] * (float)vj[u][1];
        }
      }
    }
  } else {
    // ---- generic fallback (deg > 64): strided two-pass + serial gather ----
    float4 er4 = *(const float4*)&er[d * 4];
    float m0 = NEG, m1 = NEG, m2 = NEG, m3 = NEG;
    for (int k = s0 + lane; k < s1; k += 64) {
      int s = srcv[k];
      float4 e4 = *(const float4*)&el[s * 4];
      float v;
      v = e4.x + er4.x; v = v > 0.f ? v : 0.2f * v; m0 = fmaxf(m0, v);
      v = e4.y + er4.y; v = v > 0.f ? v : 0.2f * v; m1 = fmaxf(m1, v);
      v = e4.z + er4.z; v = v > 0.f ? v : 0.2f * v; m2 = fmaxf(m2, v);
      v = e4.w + er4.w; v = v > 0.f ? v : 0.2f * v; m3 = fmaxf(m3, v);
    }
#pragma unroll
    for (int off = 32; off; off >>= 1) {
      m0 = fmaxf(m0, __shfl_xor(m0, off, 64));
      m1 = fmaxf(m1, __shfl_xor(m1, off, 64));
      m2 = fmaxf(m2, __shfl_xor(m2, off, 64));
      m3 = fmaxf(m3, __shfl_xor(m3, off, 64));
    }
    float S0 = 0.f, S1 = 0.f, S2 = 0.f, S3 = 0.f;
    for (int k = s0 + lane; k < s1; k += 64) {
      int s = srcv[k];
      float4 e4 = *(const float4*)&el[s * 4];
      float v;
      v = e4.x + er4.x; v = v > 0.f ? v : 0.2f * v; S0 += expf(v - m0);
      v = e4.y + er4.y; v = v > 0.f ? v : 0.2f * v; S1 += expf(v - m1);
      v = e4.z + er4.z; v = v > 0.f ? v : 0.2f * v; S2 += expf(v - m2);
      v = e4.w + er4.w; v = v > 0.f ? v : 0.2f * v; S3 += expf(v - m3);
    }
#pragma unroll
    for (int off = 32; off; off >>= 1) {
      S0 += __shfl_xor(S0, off, 64);
      S1 += __shfl_xor(S1, off, 64);
      S2 += __shfl_xor(S2, off, 64);
      S3 += __shfl_xor(S3, off, 64);
    }
    float mh = h == 0 ? m0 : h == 1 ? m1 : h == 2 ? m2 : m3;
    float Sh = h == 0 ? S0 : h == 1 ? S1 : h == 2 ? S2 : S3;
    float erh = h == 0 ? er4.x : h == 1 ? er4.y : h == 2 ? er4.z : er4.w;
    inv = 1.0f / Sh;
    for (int k = s0; k < s1; ++k) {
      int s = srcv[k];
      float v = el[s * 4 + h] + erh; v = v > 0.f ? v : 0.2f * v;
      float a = expf(v - mh);
      const f16* row = &hs[(long)s * W + c0];
      if constexpr (CPL == 4) {
        f16x4 hv = *(const f16x4*)row;
        acc[0] += a * (float)hv[0]; acc[1] += a * (float)hv[1];
        acc[2] += a * (float)hv[2]; acc[3] += a * (float)hv[3];
      } else {
        f16x2 hv = *(const f16x2*)row;
        acc[0] += a * (float)hv[0]; acc[1] += a * (float)hv[1];
      }
    }
  }
  if constexpr (OF16) {
    if constexpr (CPL == 4) {
      f16x4 o = { (f16)(acc[0] * inv), (f16)(acc[1] * inv), (f16)(acc[2] * inv), (f16)(acc[3] * inv) };
      __builtin_nontemporal_store(o, (f16x4*)&outp[obase]);
    } else {
      f16x2 o = { (f16)(acc[0] * inv), (f16)(acc[1] * inv) };
      __builtin_nontemporal_store(o, (f16x2*)&outp[obase]);
    }
  } else {
    if constexpr (CPL == 4) {
      f32x4 o = { acc[0] * inv, acc[1] * inv, acc[2] * inv, acc[3] * inv };
      __builtin_nontemporal_store(o, (f32x4*)&outp[obase]);
    } else {
      f32x2 o = { acc[0] * inv, acc[1] * inv };
      __builtin_nontemporal_store(o, (f32x2*)&outp[obase]);
    }
  }
}

// ---------- BN stats (f16 input), both sides; per-layer sum regions ----------
__global__ __launch_bounds__(256) void bn_stats2_k(const f16* __restrict__ xu, float* __restrict__ su, int Nu, int gU,
                                                   const f16* __restrict__ xi, float* __restrict__ si, int Ni) {
  const int C = 256;
  int b = blockIdx.x;
  const f16* x; float* sums; int N; int r0;
  if (b < gU) { x = xu; sums = su; N = Nu; r0 = b * 64; }
  else        { x = xi; sums = si; N = Ni; r0 = (b - gU) * 64; }
  int c = threadIdx.x;
  int r1 = min(r0 + 64, N);
  float s = 0.f, s2 = 0.f;
  for (int r = r0; r < r1; ++r) {
    float v = (float)x[(long)r * C + c];
    s += v; s2 += v * v;
  }
  atomicAdd(&sums[c], s);
  atomicAdd(&sums[C + c], s2);
}

// ---------- fused BN apply + activation -> f16 AND next-layer el/er; WAVE per node ----------
__global__ __launch_bounds__(256) void bn_fused_k(
    const f16* __restrict__ xu, const float* __restrict__ su, const float* __restrict__ gbu,
    f16* __restrict__ yu, int Nu,
    const f16* __restrict__ xi, const float* __restrict__ si, const float* __restrict__ gbi,
    f16* __restrict__ yi, int Ni,
    const float* __restrict__ efu, const float* __restrict__ efiu,   // next-layer folds, K=256
    float* __restrict__ el_u, float* __restrict__ er_u,
    float* __restrict__ el_i, float* __restrict__ er_i, int act) {
  const int Kn = 256;
  int wv = threadIdx.x >> 6, lane = threadIdx.x & 63;
  int g = blockIdx.x * 4 + wv;
  const f16* x; const float* sums; const float* gb; f16* y; int n; int N;
  const float* elf; const float* erf; float* el; float* er;
  if (g < Nu)           { x = xu; sums = su; gb = gbu; y = yu; n = g; N = Nu; elf = efu;  erf = efiu + 4 * Kn; el = el_u; er = er_u; }
  else if (g < Nu + Ni) { x = xi; sums = si; gb = gbi; y = yi; n = g - Nu; N = Ni; elf = efiu; erf = efu + 4 * Kn;  el = el_i; er = er_i; }
  else return;
  long base = (long)n * 256;
  int c0 = lane * 4;
  f16x4 xv = *(const f16x4*)&x[base + c0];
  float4 sm = *(const float4*)&sums[c0];
  float4 q2 = *(const float4*)&sums[256 + c0];
  float4 gg = *(const float4*)&gb[c0];
  float4 bb = *(const float4*)&gb[256 + c0];
  float ms[4] = { sm.x, sm.y, sm.z, sm.w };
  float qs[4] = { q2.x, q2.y, q2.z, q2.w };
  float gs[4] = { gg.x, gg.y, gg.z, gg.w };
  float bs[4] = { bb.x, bb.y, bb.z, bb.w };
  float inv_n = 1.0f / (float)N;
  float v[4];
  f16x4 ov;
#pragma unroll
  for (int q = 0; q < 4; ++q) {
    float mean = ms[q] * inv_n;
    float var = qs[q] * inv_n - mean * mean;
    float t = gs[q] * ((float)xv[q] - mean) * rsqrtf(var + 1e-5f) + bs[q];
    t = act ? tanhf(t) : (t > 0.f ? t : 0.01f * t);
    v[q] = t;
    ov[q] = (f16)t;
  }
  *(f16x4*)&y[base + c0] = ov;
  float p[8];
#pragma unroll
  for (int jj = 0; jj < 8; ++jj) {
    const float* fr = (jj < 4) ? (elf + jj * Kn) : (erf + (jj - 4) * Kn);
    float4 f4 = *(const float4*)&fr[c0];
    p[jj] = v[0] * f4.x + v[1] * f4.y + v[2] * f4.z + v[3] * f4.w;
  }
#pragma unroll
  for (int off = 32; off; off >>= 1)
#pragma unroll
    for (int jj = 0; jj < 8; ++jj) p[jj] += __shfl_xor(p[jj], off, 64);
  if (lane == 0) {
    *(float4*)&el[n * 4] = make_float4(p[0], p[1], p[2], p[3]);
    *(float4*)&er[n * 4] = make_float4(p[4], p[5], p[6], p[7]);
  }
}

extern "C" void kernel_launch(void* const* d_in, const int* in_sizes, int n_in,
                              void* d_out, int out_size, void* d_ws, size_t ws_size,
                              hipStream_t stream) {
  const float* x_user = (const float*)d_in[0];
  const float* x_item = (const float*)d_in[1];
  const int* eu = (const int*)d_in[2];
  const int* ei = (const int*)d_in[3];
  const float *Wm[4][2], *Am[4][2];
  for (int L = 0; L < 4; ++L) {
    Wm[L][0] = (const float*)d_in[4 + L * 4 + 0];
    Am[L][0] = (const float*)d_in[4 + L * 4 + 1];
    Wm[L][1] = (const float*)d_in[4 + L * 4 + 2];
    Am[L][1] = (const float*)d_in[4 + L * 4 + 3];
  }
  const float* bnu = (const float*)d_in[20];
  const float* bni = (const float*)d_in[21];
  float* out = (float*)d_out;

  const int NALL = NITEMS + NUSERS;

  float* ws = (float*)d_ws;
  size_t o = 0;
  float* el_u = ws + o; o += (size_t)NUSERS * 4;
  float* er_u = ws + o; o += (size_t)NUSERS * 4;
  float* el_i = ws + o; o += (size_t)NITEMS * 4;
  float* er_i = ws + o; o += (size_t)NITEMS * 4;
  float* ef_all[4][2];
  for (int L = 0; L < 4; ++L)
    for (int rl = 0; rl < 2; ++rl) { ef_all[L][rl] = ws + o; o += 2048; }
  // f16 buffers (offsets in float units; all 16B aligned)
  f16* hb_u   = (f16*)(ws + o); o += (size_t)NUSERS * 128;
  f16* hb_i   = (f16*)(ws + o); o += (size_t)NITEMS * 128;
  f16* hsb_u  = (f16*)(ws + o); o += (size_t)NUSERS * 128;
  f16* hsb_i  = (f16*)(ws + o); o += (size_t)NITEMS * 128;
  f16* aggh_u = (f16*)(ws + o); o += (size_t)NUSERS * 128;
  f16* aggh_i = (f16*)(ws + o); o += (size_t)NITEMS * 128;
  f16* Bt_all[4][2];
  for (int L = 0; L < 4; ++L) {
    int K = (L == 0) ? 128 : 256;
    int W = (L == 3) ? 128 : 256;
    for (int rl = 0; rl < 2; ++rl) { Bt_all[L][rl] = (f16*)(ws + o); o += (size_t)K * W / 2; }
  }
  // BN sums (3 layers x (512u + 512i)) + unified CSR deg: contiguous => single memset
  float* bns_all = ws + o; o += 3 * 1024;
  int* deg_all    = (int*)(ws + o); o += NALL;          // items then users
  int* rowptr_all = (int*)(ws + o); o += NALL + 4;      // unified rowptr; users offset by NEDGES
  int* cur_all    = (int*)(ws + o); o += NALL;
  int* bsum       = (int*)(ws + o); o += 256;
  int* csrsrc_all = (int*)(ws + o); o += 2 * NEDGES + 4;

  const int gE2 = (2 * NEDGES + 255) / 256;
  const int nb = (NALL + 1023) / 1024;
  const int gU = (NUSERS + 63) / 64;
  const int gI = (NITEMS + 63) / 64;
  const int gNode = (NALL + 3) / 4;

  // ---- zero BN sums + deg in one memset; unified CSR build (once) ----
  hipMemsetAsync(bns_all, 0, (3 * 1024 + NALL) * sizeof(float), stream);
  hist_k<<<dim3(gE2), dim3(256), 0, stream>>>(ei, deg_all, eu, deg_all + NITEMS);
  scan1_k<<<dim3(nb), dim3(256), 0, stream>>>(deg_all, bsum, NALL);
  scan2_k<<<dim3(1), dim3(64), 0, stream>>>(bsum, nb, rowptr_all + NALL, 2 * NEDGES);
  scan3_k<<<dim3(nb), dim3(256), 0, stream>>>(deg_all, bsum, rowptr_all, cur_all, NALL);
  scat_k<<<dim3(gE2), dim3(256), 0, stream>>>(ei, eu, cur_all, csrsrc_all);

  // CSR views: items at rowptr_all[0..NITEMS], users at rowptr_all[NITEMS..NALL]
  const int* rowptr_i = rowptr_all;
  const int* rowptr_u = rowptr_all + NITEMS;

  // ---- all layer preps upfront (tiled Bt transpose + el/er folds) ----
  for (int L = 0; L < 4; ++L) {
    int K = (L == 0) ? 128 : 256;
    int dh = (L == 3) ? 32 : 64;
    int W = 4 * dh;
    int ntile2 = 2 * (K / 32) * (W / 32);
    int gef = (2 * K * 8 + 255) / 256;
    prep2_k<<<dim3(ntile2 + gef), dim3(256), 0, stream>>>(
        Wm[L][0], Am[L][0], Bt_all[L][0], ef_all[L][0],
        Wm[L][1], Am[L][1], Bt_all[L][1], ef_all[L][1], K, W, dh);
  }

  // layer-0: fused f32->f16 convert + el/er (wave per node)
  eler2_k<<<dim3(gNode), dim3(256), 0, stream>>>(
      x_user, hb_u, ef_all[0][0], ef_all[0][1], el_u, er_u,
      x_item, hb_i, el_i, er_i);

  int K = 128;
  const int gAgg = gNode;
  const int gya = (NUSERS + 127) / 128, gyb = (NITEMS + 127) / 128;
  for (int L = 0; L < 4; ++L) {
    const int dh = (L == 3) ? 32 : 64;
    const int W = 4 * dh;

    hgemm2_k<<<dim3(W / 128, gya + gyb), dim3(256), 0, stream>>>(
        hb_u, Bt_all[L][0], hsb_u, NUSERS, gya, hb_i, Bt_all[L][1], hsb_i, NITEMS, W, K);

    if (L < 3) {
      float* su = bns_all + (size_t)L * 1024;
      float* si = su + 512;
      agg_k<256, 64, f16><<<dim3(gAgg), dim3(256), 0, stream>>>(
          el_u, er_i, rowptr_i, csrsrc_all, hsb_u, aggh_i, NITEMS,
          el_i, er_u, rowptr_u, csrsrc_all, hsb_i, aggh_u, NUSERS);
      bn_stats2_k<<<dim3(gU + gI), dim3(256), 0, stream>>>(aggh_u, su, NUSERS, gU, aggh_i, si, NITEMS);
      bn_fused_k<<<dim3(gNode), dim3(256), 0, stream>>>(
          aggh_u, su, bnu + L * 512, hb_u, NUSERS,
          aggh_i, si, bni + L * 512, hb_i, NITEMS,
          ef_all[L + 1][0], ef_all[L + 1][1],
          el_u, er_u, el_i, er_i, L == 2);
      K = 256;
    } else {
      agg_k<128, 32, float><<<dim3(gAgg), dim3(256), 0, stream>>>(
          el_u, er_i, rowptr_i, csrsrc_all, hsb_u, out + (size_t)NUSERS * 128, NITEMS,
          el_i, er_u, rowptr_u, csrsrc_all, hsb_i, out, NUSERS);
    }
  }
}

// Round 11
// 843.624 us; speedup vs baseline: 2.1174x; 1.0224x over previous
//
#include <hip/hip_runtime.h>

#define NUSERS 50000
#define NITEMS 20000
#define NEDGES 400000

typedef _Float16 f16;
typedef __attribute__((ext_vector_type(8))) _Float16 f16x8;
typedef __attribute__((ext_vector_type(4))) _Float16 f16x4;
typedef __attribute__((ext_vector_type(2))) _Float16 f16x2;
typedef __attribute__((ext_vector_type(4))) float f32x4;
typedef __attribute__((ext_vector_type(2))) float f32x2;

// ---------- prep: LDS-tiled weight transpose->f16 (coalesced both sides)
// + folded el/er projections; both relations in one launch ----------
__global__ __launch_bounds__(256) void prep2_k(
    const float* __restrict__ Wa, const float* __restrict__ Aa,
    f16* __restrict__ Bta, float* __restrict__ efa,
    const float* __restrict__ Wb, const float* __restrict__ Ab,
    f16* __restrict__ Btb, float* __restrict__ efb,
    int K, int Nw, int dh) {
  __shared__ float lds[32][33];
  int ntile = (K >> 5) * (Nw >> 5);
  int b = blockIdx.x, t = threadIdx.x;
  if (b < 2 * ntile) {
    const float* W = (b < ntile) ? Wa : Wb;
    f16* Bt = (b < ntile) ? Bta : Btb;
    int tt = (b < ntile) ? b : b - ntile;
    int ntc = Nw >> 5;
    int tr = tt / ntc, tc = tt - tr * ntc;
    int tx = t & 31, ty = t >> 5;
#pragma unroll
    for (int p = 0; p < 4; ++p) {
      int k = tr * 32 + ty + p * 8;
      int n = tc * 32 + tx;
      lds[ty + p * 8][tx] = W[(long)k * Nw + n];
    }
    __syncthreads();
#pragma unroll
    for (int p = 0; p < 4; ++p) {
      int n = tc * 32 + ty + p * 8;
      int k = tr * 32 + tx;
      Bt[(long)n * K + k] = (f16)lds[tx][ty + p * 8];
    }
  } else {
    int idx = (b - 2 * ntile) * 256 + t;
    if (idx >= 2 * K * 8) return;
    const float* W = (idx < K * 8) ? Wa : Wb;
    const float* A = (idx < K * 8) ? Aa : Ab;
    float* ef = (idx < K * 8) ? efa : efb;
    int t2 = (idx < K * 8) ? idx : idx - K * 8;
    int j = t2 / (K * 4);
    int r = t2 - j * K * 4;
    int h = r / K, f = r - h * K;
    const float* Aj = A + j * Nw;   // A[j], shape [4,dh], Nw = 4*dh
    float s = 0.f;
    for (int d = 0; d < dh; ++d) s += W[f * Nw + h * dh + d] * Aj[h * dh + d];
    ef[j * 4 * K + h * K + f] = s;
  }
}

// ---------- f16 MFMA GEMM, user+item fused: C = A[M,K] @ Bt[N,K]^T ----------
__global__ __launch_bounds__(256) void hgemm2_k(const f16* __restrict__ Aa, const f16* __restrict__ Bta,
                                                f16* __restrict__ Ca, int Ma, int gya,
                                                const f16* __restrict__ Ab, const f16* __restrict__ Btb,
                                                f16* __restrict__ Cb, int Mb,
                                                int N, int K) {
  __shared__ f16 As[128 * 32];
  __shared__ f16 Bs[128 * 32];
  int by = blockIdx.y;
  const f16* A; const f16* Bt; f16* C; int M; int row0;
  if (by < gya) { A = Aa; Bt = Bta; C = Ca; M = Ma; row0 = by * 128; }
  else          { A = Ab; Bt = Btb; C = Cb; M = Mb; row0 = (by - gya) * 128; }
  int tid = threadIdx.x;
  int col0 = blockIdx.x * 128;
  int lane = tid & 63, wv = tid >> 6;
  int wr = (wv & 1) * 64, wc = (wv >> 1) * 64;
  int l16 = lane & 15, q = lane >> 4;
  f32x4 acc[4][4] = {};
  int r = tid >> 2, c8 = (tid & 3) * 8;
  for (int k0 = 0; k0 < K; k0 += 32) {
    int ra = min(row0 + r, M - 1);
    uint4 va = *(const uint4*)&A[(long)ra * K + k0 + c8];
    int ra2 = min(row0 + r + 64, M - 1);
    uint4 va2 = *(const uint4*)&A[(long)ra2 * K + k0 + c8];
    uint4 vb = *(const uint4*)&Bt[(long)(col0 + r) * K + k0 + c8];
    uint4 vb2 = *(const uint4*)&Bt[(long)(col0 + r + 64) * K + k0 + c8];
    *(uint4*)&As[r * 32 + c8] = va;
    *(uint4*)&As[(r + 64) * 32 + c8] = va2;
    *(uint4*)&Bs[r * 32 + c8] = vb;
    *(uint4*)&Bs[(r + 64) * 32 + c8] = vb2;
    __syncthreads();
    f16x8 af[4], bfr[4];
#pragma unroll
    for (int i = 0; i < 4; ++i) {
      af[i] = *(const f16x8*)&As[(wr + i * 16 + l16) * 32 + q * 8];
      bfr[i] = *(const f16x8*)&Bs[(wc + i * 16 + l16) * 32 + q * 8];
    }
#pragma unroll
    for (int i = 0; i < 4; ++i)
#pragma unroll
      for (int j = 0; j < 4; ++j)
        acc[i][j] = __builtin_amdgcn_mfma_f32_16x16x32_f16(af[i], bfr[j], acc[i][j], 0, 0, 0);
    __syncthreads();
  }
#pragma unroll
  for (int i = 0; i < 4; ++i) {
#pragma unroll
    for (int reg = 0; reg < 4; ++reg) {
      int rr = row0 + wr + i * 16 + q * 4 + reg;
      if (rr < M) {
#pragma unroll
        for (int j = 0; j < 4; ++j)
          C[(long)rr * N + col0 + wc + j * 16 + l16] = (f16)acc[i][j][reg];
      }
    }
  }
}

// ---------- layer-0: fused f32->f16 convert + el/er folds; WAVE per node ----------
__global__ __launch_bounds__(256) void eler2_k(
    const float* __restrict__ xu, f16* __restrict__ hbu,
    const float* __restrict__ ef_ui, const float* __restrict__ ef_iu,
    float* __restrict__ el_u, float* __restrict__ er_u,
    const float* __restrict__ xi, f16* __restrict__ hbi,
    float* __restrict__ el_i, float* __restrict__ er_i) {
  const int K = 128;
  int wv = threadIdx.x >> 6, lane = threadIdx.x & 63;
  int g = blockIdx.x * 4 + wv;
  const float* x; f16* hb; const float* elf; const float* erf; float* el; float* er; int n;
  if (g < NUSERS)                { x = xu; hb = hbu; elf = ef_ui; erf = ef_iu + 4 * K; el = el_u; er = er_u; n = g; }
  else if (g < NUSERS + NITEMS)  { x = xi; hb = hbi; elf = ef_iu; erf = ef_ui + 4 * K; el = el_i; er = er_i; n = g - NUSERS; }
  else return;
  long base = (long)n * K;
  int c0 = lane * 2;
  f32x2 xv = *(const f32x2*)&x[base + c0];
  f16x2 hv = { (f16)xv[0], (f16)xv[1] };
  *(f16x2*)&hb[base + c0] = hv;
  float p[8];
#pragma unroll
  for (int jj = 0; jj < 8; ++jj) {
    const float* fr = (jj < 4) ? (elf + jj * K) : (erf + (jj - 4) * K);
    f32x2 f2 = *(const f32x2*)&fr[c0];
    p[jj] = xv[0] * f2[0] + xv[1] * f2[1];
  }
#pragma unroll
  for (int off = 32; off; off >>= 1)
#pragma unroll
    for (int jj = 0; jj < 8; ++jj) p[jj] += __shfl_xor(p[jj], off, 64);
  if (lane == 0) {
    *(float4*)&el[n * 4] = make_float4(p[0], p[1], p[2], p[3]);
    *(float4*)&er[n * 4] = make_float4(p[4], p[5], p[6], p[7]);
  }
}

// ---------- CSR build (unified: items [0,NITEMS) then users [NITEMS,NITEMS+NUSERS)) ----------
__global__ void hist_k(const int* __restrict__ ei, int* __restrict__ degi,
                       const int* __restrict__ eu, int* __restrict__ degu) {
  int e = blockIdx.x * blockDim.x + threadIdx.x;
  if (e < NEDGES) atomicAdd(&degi[ei[e]], 1);
  else if (e < 2 * NEDGES) atomicAdd(&degu[eu[e - NEDGES]], 1);
}

__global__ __launch_bounds__(256) void scan1_k(const int* __restrict__ deg,
                                               int* __restrict__ bsum, int N) {
  __shared__ int red[256];
  int base = blockIdx.x * 1024, t = threadIdx.x;
  int s = 0;
#pragma unroll
  for (int j = 0; j < 4; ++j) { int i = base + t * 4 + j; s += (i < N) ? deg[i] : 0; }
  red[t] = s; __syncthreads();
  for (int off = 128; off; off >>= 1) { if (t < off) red[t] += red[t + off]; __syncthreads(); }
  if (t == 0) bsum[blockIdx.x] = red[0];
}

// exclusive block-sum scan + writes rowptr[N] terminator
__global__ void scan2_k(int* __restrict__ bsum, int nb, int* __restrict__ endp, int endv) {
  if (threadIdx.x == 0) {
    int run = 0;
    for (int i = 0; i < nb; ++i) { int v = bsum[i]; bsum[i] = run; run += v; }
    *endp = endv;
  }
}

// scan3 also writes cur[] (folds old copy2_k)
__global__ __launch_bounds__(256) void scan3_k(const int* __restrict__ deg,
                                               const int* __restrict__ bsum,
                                               int* __restrict__ rowptr,
                                               int* __restrict__ cur, int N) {
  __shared__ int tsum[256];
  int base = blockIdx.x * 1024, t = threadIdx.x;
  int v[4]; int s = 0;
#pragma unroll
  for (int j = 0; j < 4; ++j) { int i = base + t * 4 + j; v[j] = (i < N) ? deg[i] : 0; s += v[j]; }
  tsum[t] = s; __syncthreads();
  for (int off = 1; off < 256; off <<= 1) {
    int x = (t >= off) ? tsum[t - off] : 0;
    __syncthreads();
    tsum[t] += x;
    __syncthreads();
  }
  int run = bsum[blockIdx.x] + ((t > 0) ? tsum[t - 1] : 0);
#pragma unroll
  for (int j = 0; j < 4; ++j) {
    int i = base + t * 4 + j;
    if (i < N) { rowptr[i] = run; cur[i] = run; }
    run += v[j];
  }
}

// scatter: PLAIN stores -- measured floor. (NT: 59.4MB/67us; atomicExch:
// 49.8MB/71us; plain: 44.5MB/62us. Random 4B scatter across 8 non-coherent
// L2s has inherent ~14x write amplification; store-type tricks only hurt.)
__global__ void scat_k(const int* __restrict__ ei, const int* __restrict__ eu,
                       int* __restrict__ cur, int* __restrict__ csrsrc) {
  int e = blockIdx.x * blockDim.x + threadIdx.x;
  if (e < NEDGES) {
    int p = atomicAdd(&cur[ei[e]], 1);
    csrsrc[p] = eu[e];
  } else if (e < 2 * NEDGES) {
    int e2 = e - NEDGES;
    int p = atomicAdd(&cur[NITEMS + eu[e2]], 1);
    csrsrc[p] = ei[e2];
  }
}

// ---------- fused segment-softmax + gather; wave per dst ----------
// Output stores NON-TEMPORAL (measured: FETCH -4MB, keeps hs rows in L2).
template <int W, int DH, typename OUT>
__global__ __launch_bounds__(256) void agg_k(
    const float* __restrict__ elA, const float* __restrict__ erA,
    const int* __restrict__ rpA, const int* __restrict__ srcA,
    const f16* __restrict__ hsA, OUT* __restrict__ outA, int nA,
    const float* __restrict__ elB, const float* __restrict__ erB,
    const int* __restrict__ rpB, const int* __restrict__ srcB,
    const f16* __restrict__ hsB, OUT* __restrict__ outB, int nB) {
  constexpr int CPL = W >> 6;                   // channels per lane
  constexpr int SHIFT = (W == 256) ? 9 : 8;     // log2(W * sizeof(f16))
  constexpr bool OF16 = (sizeof(OUT) == 2);
  __shared__ float alds[4][256];   // [wave][slot*4 + head]
  __shared__ int soff[4][64];      // [wave][slot] = src row byte offset
  int wv = threadIdx.x >> 6;
  int g = blockIdx.x * 4 + wv;
  int lane = threadIdx.x & 63;
  const float* el; const float* er; const int* rp; const int* srcv;
  const f16* hs; OUT* outp; int d;
  if (g < nA)           { el = elA; er = erA; rp = rpA; srcv = srcA; hs = hsA; outp = outA; d = g; }
  else if (g < nA + nB) { el = elB; er = erB; rp = rpB; srcv = srcB; hs = hsB; outp = outB; d = g - nA; }
  else return;
  int s0 = rp[d], s1 = rp[d + 1];
  int deg = s1 - s0;
  int c0 = lane * CPL;
  int h = c0 / DH;
  long obase = (long)d * W + c0;
  if (deg == 0) {
#pragma unroll
    for (int q = 0; q < CPL; ++q) outp[obase + q] = (OUT)0.f;
    return;
  }
  const float NEG = -3.0e38f;
  float acc[CPL];
#pragma unroll
  for (int q = 0; q < CPL; ++q) acc[q] = 0.f;
  float inv;

  if (deg <= 64) {
    int hh = lane & 3, p = lane >> 2;
    float er_h = er[d * 4 + hh];
    float vv[4];
    float vmax = NEG;
#pragma unroll
    for (int j = 0; j < 4; ++j) {
      int slot = j * 16 + p;
      vv[j] = NEG;
      if (slot < deg) {
        int sj = srcv[s0 + slot];
        if (hh == 0) soff[wv][slot] = sj << SHIFT;
        float v = el[sj * 4 + hh] + er_h;
        v = v > 0.f ? v : 0.2f * v;
        vv[j] = v;
        vmax = fmaxf(vmax, v);
      }
    }
#pragma unroll
    for (int off = 4; off < 64; off <<= 1) vmax = fmaxf(vmax, __shfl_xor(vmax, off, 64));
    float ssum = 0.f;
#pragma unroll
    for (int j = 0; j < 4; ++j) {
      int slot = j * 16 + p;
      if (slot < deg) {
        float e = expf(vv[j] - vmax);
        alds[wv][slot * 4 + hh] = e;
        ssum += e;
      } else {
        alds[wv][slot * 4 + hh] = 0.f;       // zero-pad alpha
        if (hh == 0) soff[wv][slot] = 0;     // pad offset -> row 0 (always cached)
      }
    }
#pragma unroll
    for (int off = 4; off < 64; off <<= 1) ssum += __shfl_xor(ssum, off, 64);
    float Sh = __shfl(ssum, (lane & ~3) | h, 64);
    inv = 1.0f / Sh;
    const char* hbase = (const char*)hs + (size_t)c0 * sizeof(f16);
    int degp = (deg + 3) & ~3;
    for (int j = 0; j < degp; j += 4) {
      float aj[4]; int oj[4];
#pragma unroll
      for (int u = 0; u < 4; ++u) {
        aj[u] = alds[wv][(j + u) * 4 + h];
        oj[u] = soff[wv][j + u];
      }
      if constexpr (CPL == 4) {
        f16x4 vj[4];
#pragma unroll
        for (int u = 0; u < 4; ++u)
          vj[u] = *(const f16x4*)(hbase + (size_t)(unsigned)oj[u]);
#pragma unroll
        for (int u = 0; u < 4; ++u) {
          acc[0] += aj[u] * (float)vj[u][0];
          acc[1] += aj[u] * (float)vj[u][1];
          acc[2] += aj[u] * (float)vj[u][2];
          acc[3] += aj[u] * (float)vj[u][3];
        }
      } else {
        f16x2 vj[4];
#pragma unroll
        for (int u = 0; u < 4; ++u)
          vj[u] = *(const f16x2*)(hbase + (size_t)(unsigned)oj[u]);
#pragma unroll
        for (int u = 0; u < 4; ++u) {
          acc[0] += aj[u] * (float)vj[u][0];
          acc[1] += aj[u] * (float)vj[u][1];
        }
      }
    }
  } else {
    // ---- generic fallback (deg > 64): strided two-pass + serial gather ----
    float4 er4 = *(const float4*)&er[d * 4];
    float m0 = NEG, m1 = NEG, m2 = NEG, m3 = NEG;
    for (int k = s0 + lane; k < s1; k += 64) {
      int s = srcv[k];
      float4 e4 = *(const float4*)&el[s * 4];
      float v;
      v = e4.x + er4.x; v = v > 0.f ? v : 0.2f * v; m0 = fmaxf(m0, v);
      v = e4.y + er4.y; v = v > 0.f ? v : 0.2f * v; m1 = fmaxf(m1, v);
      v = e4.z + er4.z; v = v > 0.f ? v : 0.2f * v; m2 = fmaxf(m2, v);
      v = e4.w + er4.w; v = v > 0.f ? v : 0.2f * v; m3 = fmaxf(m3, v);
    }
#pragma unroll
    for (int off = 32; off; off >>= 1) {
      m0 = fmaxf(m0, __shfl_xor(m0, off, 64));
      m1 = fmaxf(m1, __shfl_xor(m1, off, 64));
      m2 = fmaxf(m2, __shfl_xor(m2, off, 64));
      m3 = fmaxf(m3, __shfl_xor(m3, off, 64));
    }
    float S0 = 0.f, S1 = 0.f, S2 = 0.f, S3 = 0.f;
    for (int k = s0 + lane; k < s1; k += 64) {
      int s = srcv[k];
      float4 e4 = *(const float4*)&el[s * 4];
      float v;
      v = e4.x + er4.x; v = v > 0.f ? v : 0.2f * v; S0 += expf(v - m0);
      v = e4.y + er4.y; v = v > 0.f ? v : 0.2f * v; S1 += expf(v - m1);
      v = e4.z + er4.z; v = v > 0.f ? v : 0.2f * v; S2 += expf(v - m2);
      v = e4.w + er4.w; v = v > 0.f ? v : 0.2f * v; S3 += expf(v - m3);
    }
#pragma unroll
    for (int off = 32; off; off >>= 1) {
      S0 += __shfl_xor(S0, off, 64);
      S1 += __shfl_xor(S1, off, 64);
      S2 += __shfl_xor(S2, off, 64);
      S3 += __shfl_xor(S3, off, 64);
    }
    float mh = h == 0 ? m0 : h == 1 ? m1 : h == 2 ? m2 : m3;
    float Sh = h == 0 ? S0 : h == 1 ? S1 : h == 2 ? S2 : S3;
    float erh = h == 0 ? er4.x : h == 1 ? er4.y : h == 2 ? er4.z : er4.w;
    inv = 1.0f / Sh;
    for (int k = s0; k < s1; ++k) {
      int s = srcv[k];
      float v = el[s * 4 + h] + erh; v = v > 0.f ? v : 0.2f * v;
      float a = expf(v - mh);
      const f16* row = &hs[(long)s * W + c0];
      if constexpr (CPL == 4) {
        f16x4 hv = *(const f16x4*)row;
        acc[0] += a * (float)hv[0]; acc[1] += a * (float)hv[1];
        acc[2] += a * (float)hv[2]; acc[3] += a * (float)hv[3];
      } else {
        f16x2 hv = *(const f16x2*)row;
        acc[0] += a * (float)hv[0]; acc[1] += a * (float)hv[1];
      }
    }
  }
  if constexpr (OF16) {
    if constexpr (CPL == 4) {
      f16x4 o = { (f16)(acc[0] * inv), (f16)(acc[1] * inv), (f16)(acc[2] * inv), (f16)(acc[3] * inv) };
      __builtin_nontemporal_store(o, (f16x4*)&outp[obase]);
    } else {
      f16x2 o = { (f16)(acc[0] * inv), (f16)(acc[1] * inv) };
      __builtin_nontemporal_store(o, (f16x2*)&outp[obase]);
    }
  } else {
    if constexpr (CPL == 4) {
      f32x4 o = { acc[0] * inv, acc[1] * inv, acc[2] * inv, acc[3] * inv };
      __builtin_nontemporal_store(o, (f32x4*)&outp[obase]);
    } else {
      f32x2 o = { acc[0] * inv, acc[1] * inv };
      __builtin_nontemporal_store(o, (f32x2*)&outp[obase]);
    }
  }
}

// ---------- BN stats (f16 input), both sides; per-layer sum regions ----------
__global__ __launch_bounds__(256) void bn_stats2_k(const f16* __restrict__ xu, float* __restrict__ su, int Nu, int gU,
                                                   const f16* __restrict__ xi, float* __restrict__ si, int Ni) {
  const int C = 256;
  int b = blockIdx.x;
  const f16* x; float* sums; int N; int r0;
  if (b < gU) { x = xu; sums = su; N = Nu; r0 = b * 64; }
  else        { x = xi; sums = si; N = Ni; r0 = (b - gU) * 64; }
  int c = threadIdx.x;
  int r1 = min(r0 + 64, N);
  float s = 0.f, s2 = 0.f;
  for (int r = r0; r < r1; ++r) {
    float v = (float)x[(long)r * C + c];
    s += v; s2 += v * v;
  }
  atomicAdd(&sums[c], s);
  atomicAdd(&sums[C + c], s2);
}

// ---------- fused BN apply + activation -> f16 AND next-layer el/er; WAVE per node ----------
__global__ __launch_bounds__(256) void bn_fused_k(
    const f16* __restrict__ xu, const float* __restrict__ su, const float* __restrict__ gbu,
    f16* __restrict__ yu, int Nu,
    const f16* __restrict__ xi, const float* __restrict__ si, const float* __restrict__ gbi,
    f16* __restrict__ yi, int Ni,
    const float* __restrict__ efu, const float* __restrict__ efiu,   // next-layer folds, K=256
    float* __restrict__ el_u, float* __restrict__ er_u,
    float* __restrict__ el_i, float* __restrict__ er_i, int act) {
  const int Kn = 256;
  int wv = threadIdx.x >> 6, lane = threadIdx.x & 63;
  int g = blockIdx.x * 4 + wv;
  const f16* x; const float* sums; const float* gb; f16* y; int n; int N;
  const float* elf; const float* erf; float* el; float* er;
  if (g < Nu)           { x = xu; sums = su; gb = gbu; y = yu; n = g; N = Nu; elf = efu;  erf = efiu + 4 * Kn; el = el_u; er = er_u; }
  else if (g < Nu + Ni) { x = xi; sums = si; gb = gbi; y = yi; n = g - Nu; N = Ni; elf = efiu; erf = efu + 4 * Kn;  el = el_i; er = er_i; }
  else return;
  long base = (long)n * 256;
  int c0 = lane * 4;
  f16x4 xv = *(const f16x4*)&x[base + c0];
  float4 sm = *(const float4*)&sums[c0];
  float4 q2 = *(const float4*)&sums[256 + c0];
  float4 gg = *(const float4*)&gb[c0];
  float4 bb = *(const float4*)&gb[256 + c0];
  float ms[4] = { sm.x, sm.y, sm.z, sm.w };
  float qs[4] = { q2.x, q2.y, q2.z, q2.w };
  float gs[4] = { gg.x, gg.y, gg.z, gg.w };
  float bs[4] = { bb.x, bb.y, bb.z, bb.w };
  float inv_n = 1.0f / (float)N;
  float v[4];
  f16x4 ov;
#pragma unroll
  for (int q = 0; q < 4; ++q) {
    float mean = ms[q] * inv_n;
    float var = qs[q] * inv_n - mean * mean;
    float t = gs[q] * ((float)xv[q] - mean) * rsqrtf(var + 1e-5f) + bs[q];
    t = act ? tanhf(t) : (t > 0.f ? t : 0.01f * t);
    v[q] = t;
    ov[q] = (f16)t;
  }
  *(f16x4*)&y[base + c0] = ov;
  float p[8];
#pragma unroll
  for (int jj = 0; jj < 8; ++jj) {
    const float* fr = (jj < 4) ? (elf + jj * Kn) : (erf + (jj - 4) * Kn);
    float4 f4 = *(const float4*)&fr[c0];
    p[jj] = v[0] * f4.x + v[1] * f4.y + v[2] * f4.z + v[3] * f4.w;
  }
#pragma unroll
  for (int off = 32; off; off >>= 1)
#pragma unroll
    for (int jj = 0; jj < 8; ++jj) p[jj] += __shfl_xor(p[jj], off, 64);
  if (lane == 0) {
    *(float4*)&el[n * 4] = make_float4(p[0], p[1], p[2], p[3]);
    *(float4*)&er[n * 4] = make_float4(p[4], p[5], p[6], p[7]);
  }
}

extern "C" void kernel_launch(void* const* d_in, const int* in_sizes, int n_in,
                              void* d_out, int out_size, void* d_ws, size_t ws_size,
                              hipStream_t stream) {
  const float* x_user = (const float*)d_in[0];
  const float* x_item = (const float*)d_in[1];
  const int* eu = (const int*)d_in[2];
  const int* ei = (const int*)d_in[3];
  const float *Wm[4][2], *Am[4][2];
  for (int L = 0; L < 4; ++L) {
    Wm[L][0] = (const float*)d_in[4 + L * 4 + 0];
    Am[L][0] = (const float*)d_in[4 + L * 4 + 1];
    Wm[L][1] = (const float*)d_in[4 + L * 4 + 2];
    Am[L][1] = (const float*)d_in[4 + L * 4 + 3];
  }
  const float* bnu = (const float*)d_in[20];
  const float* bni = (const float*)d_in[21];
  float* out = (float*)d_out;

  const int NALL = NITEMS + NUSERS;

  float* ws = (float*)d_ws;
  size_t o = 0;
  float* el_u = ws + o; o += (size_t)NUSERS * 4;
  float* er_u = ws + o; o += (size_t)NUSERS * 4;
  float* el_i = ws + o; o += (size_t)NITEMS * 4;
  float* er_i = ws + o; o += (size_t)NITEMS * 4;
  float* ef_all[4][2];
  for (int L = 0; L < 4; ++L)
    for (int rl = 0; rl < 2; ++rl) { ef_all[L][rl] = ws + o; o += 2048; }
  // f16 buffers (offsets in float units; all 16B aligned)
  f16* hb_u   = (f16*)(ws + o); o += (size_t)NUSERS * 128;
  f16* hb_i   = (f16*)(ws + o); o += (size_t)NITEMS * 128;
  f16* hsb_u  = (f16*)(ws + o); o += (size_t)NUSERS * 128;
  f16* hsb_i  = (f16*)(ws + o); o += (size_t)NITEMS * 128;
  f16* aggh_u = (f16*)(ws + o); o += (size_t)NUSERS * 128;
  f16* aggh_i = (f16*)(ws + o); o += (size_t)NITEMS * 128;
  f16* Bt_all[4][2];
  for (int L = 0; L < 4; ++L) {
    int K = (L == 0) ? 128 : 256;
    int W = (L == 3) ? 128 : 256;
    for (int rl = 0; rl < 2; ++rl) { Bt_all[L][rl] = (f16*)(ws + o); o += (size_t)K * W / 2; }
  }
  // BN sums (3 layers x (512u + 512i)) + unified CSR deg: contiguous => single memset
  float* bns_all = ws + o; o += 3 * 1024;
  int* deg_all    = (int*)(ws + o); o += NALL;          // items then users
  int* rowptr_all = (int*)(ws + o); o += NALL + 4;      // unified rowptr; users offset by NEDGES
  int* cur_all    = (int*)(ws + o); o += NALL;
  int* bsum       = (int*)(ws + o); o += 256;
  int* csrsrc_all = (int*)(ws + o); o += 2 * NEDGES + 4;

  const int gE2 = (2 * NEDGES + 255) / 256;
  const int nb = (NALL + 1023) / 1024;
  const int gU = (NUSERS + 63) / 64;
  const int gI = (NITEMS + 63) / 64;
  const int gNode = (NALL + 3) / 4;

  // ---- zero BN sums + deg in one memset; unified CSR build (once) ----
  hipMemsetAsync(bns_all, 0, (3 * 1024 + NALL) * sizeof(float), stream);
  hist_k<<<dim3(gE2), dim3(256), 0, stream>>>(ei, deg_all, eu, deg_all + NITEMS);
  scan1_k<<<dim3(nb), dim3(256), 0, stream>>>(deg_all, bsum, NALL);
  scan2_k<<<dim3(1), dim3(64), 0, stream>>>(bsum, nb, rowptr_all + NALL, 2 * NEDGES);
  scan3_k<<<dim3(nb), dim3(256), 0, stream>>>(deg_all, bsum, rowptr_all, cur_all, NALL);
  scat_k<<<dim3(gE2), dim3(256), 0, stream>>>(ei, eu, cur_all, csrsrc_all);

  // CSR views: items at rowptr_all[0..NITEMS], users at rowptr_all[NITEMS..NALL]
  const int* rowptr_i = rowptr_all;
  const int* rowptr_u = rowptr_all + NITEMS;

  // ---- all layer preps upfront (tiled Bt transpose + el/er folds) ----
  for (int L = 0; L < 4; ++L) {
    int K = (L == 0) ? 128 : 256;
    int dh = (L == 3) ? 32 : 64;
    int W = 4 * dh;
    int ntile2 = 2 * (K / 32) * (W / 32);
    int gef = (2 * K * 8 + 255) / 256;
    prep2_k<<<dim3(ntile2 + gef), dim3(256), 0, stream>>>(
        Wm[L][0], Am[L][0], Bt_all[L][0], ef_all[L][0],
        Wm[L][1], Am[L][1], Bt_all[L][1], ef_all[L][1], K, W, dh);
  }

  // layer-0: fused f32->f16 convert + el/er (wave per node)
  eler2_k<<<dim3(gNode), dim3(256), 0, stream>>>(
      x_user, hb_u, ef_all[0][0], ef_all[0][1], el_u, er_u,
      x_item, hb_i, el_i, er_i);

  int K = 128;
  const int gAgg = gNode;
  const int gya = (NUSERS + 127) / 128, gyb = (NITEMS + 127) / 128;
  for (int L = 0; L < 4; ++L) {
    const int dh = (L == 3) ? 32 : 64;
    const int W = 4 * dh;

    hgemm2_k<<<dim3(W / 128, gya + gyb), dim3(256), 0, stream>>>(
        hb_u, Bt_all[L][0], hsb_u, NUSERS, gya, hb_i, Bt_all[L][1], hsb_i, NITEMS, W, K);

    if (L < 3) {
      float* su = bns_all + (size_t)L * 1024;
      float* si = su + 512;
      agg_k<256, 64, f16><<<dim3(gAgg), dim3(256), 0, stream>>>(
          el_u, er_i, rowptr_i, csrsrc_all, hsb_u, aggh_i, NITEMS,
          el_i, er_u, rowptr_u, csrsrc_all, hsb_i, aggh_u, NUSERS);
      bn_stats2_k<<<dim3(gU + gI), dim3(256), 0, stream>>>(aggh_u, su, NUSERS, gU, aggh_i, si, NITEMS);
      bn_fused_k<<<dim3(gNode), dim3(256), 0, stream>>>(
          aggh_u, su, bnu + L * 512, hb_u, NUSERS,
          aggh_i, si, bni + L * 512, hb_i, NITEMS,
          ef_all[L + 1][0], ef_all[L + 1][1],
          el_u, er_u, el_i, er_i, L == 2);
      K = 256;
    } else {
      agg_k<128, 32, float><<<dim3(gAgg), dim3(256), 0, stream>>>(
          el_u, er_i, rowptr_i, csrsrc_all, hsb_u, out + (size_t)NUSERS * 128, NITEMS,
          el_i, er_u, rowptr_u, csrsrc_all, hsb_i, out, NUSERS);
    }
  }
}